// Round 5
// baseline (252.952 us; speedup 1.0000x reference)
//
#include <hip/hip_runtime.h>

#define N_NODES 20000
#define N_REL 200
#define N_EDGES 200000
#define DIM 128
#define T_STEPS 8
#define ROWS_BLK 32
#define N_TILES32 (N_NODES / ROWS_BLK)      // 625
#define KEYS (N_NODES * T_STEPS)            // 160000 (dst,t) segments
#define SCAN_N (KEYS + 1)                   // 160001
#define SCAN_BLKS ((SCAN_N + 1023) / 1024)  // 157

typedef short short8 __attribute__((ext_vector_type(8)));
typedef float f32x4 __attribute__((ext_vector_type(4)));

static __device__ __forceinline__ unsigned short f2bf(float f) {
  union { float f; unsigned u; } v; v.f = f;
  unsigned r = v.u + 0x7fffu + ((v.u >> 16) & 1u);   // RNE
  return (unsigned short)(r >> 16);
}
// packed f32x2 -> bf16x2 (RNE), 1 instruction
static __device__ __forceinline__ unsigned cvt_pk_bf16(float lo, float hi) {
  unsigned r;
  asm("v_cvt_pk_bf16_f32 %0, %1, %2" : "=v"(r) : "v"(lo), "v"(hi));
  return r;
}
static __device__ __forceinline__ float fast_tanh(float x) {
  float e = __expf(2.f * x);           // inf-safe: x>>0 -> 1, x<<0 -> -1
  return 1.f - 2.f / (e + 1.f);
}
static __device__ __forceinline__ float fast_sig(float x) {
  return 1.f / (1.f + __expf(-x));
}

// ---------------------------------------------------------------------------
// Repack the five 128x128 fp32 weight matrices (row-major W[k][n]) into bf16
// MFMA B-fragment order: pack[m][((nt*4+ks)*64+lane)*8+j] = bf16(W[k][n]),
// n = nt*16 + (lane&15), k = ks*32 + (lane>>4)*8 + j.
// Slots: 0=Wenc 1=Wz 2=Uz 3=Wh 4=Uh.
// ---------------------------------------------------------------------------
__global__ void repack5(const float* __restrict__ w0,
                        const float* __restrict__ w1,
                        const float* __restrict__ w2,
                        const float* __restrict__ w3,
                        const float* __restrict__ w4,
                        unsigned short* __restrict__ pack) {
  int i = blockIdx.x * blockDim.x + threadIdx.x;
  if (i >= 5 * 16384) return;
  int m = i >> 14, r = i & 16383;
  int j = r & 7, lane = (r >> 3) & 63, ks = (r >> 9) & 3, nt = (r >> 11) & 7;
  int n = nt * 16 + (lane & 15);
  int k = ks * 32 + (lane >> 4) * 8 + j;
  const float* w = (m == 0) ? w0 : (m == 1) ? w1 : (m == 2) ? w2
                 : (m == 3) ? w3 : w4;
  pack[i] = f2bf(w[k * DIM + n]);
}

// ----------------- CSR build: bucket by key = dst*8 + t --------------------
__global__ void hist_k(const int* __restrict__ dst, const int* __restrict__ etime,
                       int* __restrict__ counts) {
  int i = blockIdx.x * blockDim.x + threadIdx.x;
  if (i >= N_EDGES) return;
  atomicAdd(&counts[dst[i] * T_STEPS + etime[i]], 1);
}

__global__ void scan1_k(const int* __restrict__ counts,
                        int* __restrict__ base, int* __restrict__ bsum) {
  __shared__ int ls[256];
  int tid = threadIdx.x;
  int i0 = blockIdx.x * 1024 + tid * 4;
  int v[4], ts = 0;
#pragma unroll
  for (int r = 0; r < 4; r++) {
    v[r] = (i0 + r < SCAN_N) ? counts[i0 + r] : 0;
    ts += v[r];
  }
  ls[tid] = ts; __syncthreads();
#pragma unroll
  for (int off = 1; off < 256; off <<= 1) {
    int x = (tid >= off) ? ls[tid - off] : 0;
    __syncthreads(); ls[tid] += x; __syncthreads();
  }
  int run = ls[tid] - ts;
  if (tid == 255) bsum[blockIdx.x] = ls[255];
#pragma unroll
  for (int r = 0; r < 4; r++) {
    if (i0 + r < SCAN_N) base[i0 + r] = run;
    run += v[r];
  }
}

__global__ void scan2_k(int* __restrict__ bsum) {
  __shared__ int ls[256];
  int tid = threadIdx.x;
  int v = (tid < SCAN_BLKS) ? bsum[tid] : 0;
  ls[tid] = v; __syncthreads();
#pragma unroll
  for (int off = 1; off < 256; off <<= 1) {
    int x = (tid >= off) ? ls[tid - off] : 0;
    __syncthreads(); ls[tid] += x; __syncthreads();
  }
  if (tid < SCAN_BLKS) bsum[tid] = ls[tid] - v;
}

__global__ void scan3_k(int* __restrict__ base, const int* __restrict__ bsum) {
  int i = blockIdx.x * blockDim.x + threadIdx.x;
  if (i < SCAN_N) base[i] += bsum[i >> 10];
}

// ep2 = {src | rel<<15, weight bits}; t is implicit in the segment
__global__ void fill_k(const int* __restrict__ src, const int* __restrict__ dst,
                       const int* __restrict__ etype, const int* __restrict__ etime,
                       const float* __restrict__ ew,
                       const int* __restrict__ base, int* __restrict__ cursor,
                       uint2* __restrict__ ep2) {
  int i = blockIdx.x * blockDim.x + threadIdx.x;
  if (i >= N_EDGES) return;
  int key = dst[i] * T_STEPS + etime[i];
  int pos = base[key] + atomicAdd(&cursor[key], 1);
  uint2 e;
  e.x = (unsigned)src[i] | ((unsigned)etype[i] << 15);
  e.y = __float_as_uint(ew[i]);
  ep2[pos] = e;
}

// ---------------------------------------------------------------------------
// Gather: one wave per dst node; (dst,t)-segmented edges -> plain FMA loop per
// segment; one 8B load per edge for the metadata. Row written (bf16 packed)
// at each segment end -> all 8 agg[t][node] rows covered, no memset.
// ---------------------------------------------------------------------------
__global__ void gather_k(const int* __restrict__ base,
                         const uint2* __restrict__ ep2,
                         const float* __restrict__ nemb,
                         const float* __restrict__ remb,
                         unsigned short* __restrict__ aggb) {
  int lane = threadIdx.x & 63;
  int node = (blockIdx.x * blockDim.x + threadIdx.x) >> 6;   // 0..N_NODES-1
  const int* b = base + node * T_STEPS;
  int i = b[0];
#pragma unroll
  for (int tt = 0; tt < T_STEPS; tt++) {
    int e1 = b[tt + 1];
    float ax = 0.f, ay = 0.f;
    for (; i < e1; i++) {
      uint2 e = ep2[i];
      float w = __uint_as_float(e.y);
      int s = e.x & 0x7fff, rt = e.x >> 15;
      float2 sv = ((const float2*)(nemb + (size_t)s * DIM))[lane];
      float2 rv = ((const float2*)(remb + (size_t)rt * DIM))[lane];
      ax += sv.x * rv.x * w;
      ay += sv.y * rv.y * w;
    }
    ((unsigned*)(aggb + ((size_t)tt * N_NODES + node) * DIM))[lane] =
        cvt_pk_bf16(ax, ay);
  }
}

// ---------------------------------------------------------------------------
// Fully-fused encoder + GRU recurrence, 32 ROWS PER BLOCK.
// R0/R1/R4 all sat at ~71-77 us with 16-row blocks regardless of micro
// changes; counters showed no pipe >42% busy -> latency-bound barrier convoy
// (16 MFMAs per wave per step cannot amortize gates->LDS->barrier->read->
// dependent-MFMA-chain latency, at ~1.5 resident blocks/CU).
// This version doubles the work per barrier: 8 waves, wave nt owns col-tile
// nt for TWO row-tiles rt in {0,1}. Per step per wave: 32 MFMAs arranged as
// 4 independent dependent-chains (2 rt x {z,c}) -> 4-way MFMA ILP; 2 parallel
// gate/exp streams; half the blocks (625); barriers amortized 2x.
// Weights: wave's 16 recurrence B-frags (wz,uz,wh,uh) pinned via opaque asm
// (they land in the unified AGPR side; VGPR_Count=60 in R4 confirmed
// residency, no scratch traffic). Encoder hoisted: hpk[2][8][2] u32.
// Per step t: H[t],S -> double-buffered LDS (stride 136), ONE barrier,
// re-read as A-frags (full 128-K), MFMAs, gated update.
// MFMA 16x16x32_bf16 layouts (HW-verified): A: m=lane&15,k=quad*8+j;
// B: n=lane&15,k=quad*8+j;  C/D: col=lane&15, row=quad*4+reg.
// Double-buffer WAR safety: writes of buffer X at step t+2 are ordered after
// barrier(t+1), which is after all reads of X at step t.
// ---------------------------------------------------------------------------
__launch_bounds__(512, 3)
__global__ void fused_recur(const unsigned short* __restrict__ aggb,
                            const unsigned short* __restrict__ pack,
                            const float* __restrict__ bz,
                            const float* __restrict__ bh,
                            float* __restrict__ out) {
  __shared__ unsigned short Hb[2][ROWS_BLK * 136];
  __shared__ unsigned short Sb[2][ROWS_BLK * 136];
  int lane = threadIdx.x & 63;
  int nt = threadIdx.x >> 6;        // wave id = column tile, 0..7
  int q = lane >> 4, l15 = lane & 15;
  int row0 = blockIdx.x * ROWS_BLK;
  int c = nt * 16 + l15;

  // ---- encoder for ALL steps, both row-tiles: H as packed bf16 ----
  unsigned hpk[2][T_STEPS][2];
  {
    short8 wenc[4];
#pragma unroll
    for (int ks = 0; ks < 4; ks++) {
      wenc[ks] = *(const short8*)(pack + ((nt * 4 + ks) * 64 + lane) * 8);
      asm volatile("" : "+v"(wenc[ks]));   // pin: no remat across unroll
    }
#pragma unroll
    for (int rt = 0; rt < 2; rt++) {
#pragma unroll
      for (int t = 0; t < T_STEPS; t++) {
        f32x4 acch = (f32x4){0.f, 0.f, 0.f, 0.f};
#pragma unroll
        for (int ks = 0; ks < 4; ks++) {
          short8 aA = *(const short8*)(aggb +
              ((size_t)t * N_NODES + row0 + rt * 16 + l15) * DIM + ks * 32 + q * 8);
          acch = __builtin_amdgcn_mfma_f32_16x16x32_bf16(aA, wenc[ks], acch, 0, 0, 0);
        }
        hpk[rt][t][0] = cvt_pk_bf16(fast_tanh(acch[0]), fast_tanh(acch[1]));
        hpk[rt][t][1] = cvt_pk_bf16(fast_tanh(acch[2]), fast_tanh(acch[3]));
      }
    }
  }

  // pinned recurrence weight B-fragments for this wave's nt (64 regs)
  short8 wz[4], uz[4], wh[4], uh[4];
#pragma unroll
  for (int ks = 0; ks < 4; ks++) {
    int fo = ((nt * 4 + ks) * 64 + lane) * 8;
    wz[ks] = *(const short8*)(pack + 16384 * 1 + fo);
    uz[ks] = *(const short8*)(pack + 16384 * 2 + fo);
    wh[ks] = *(const short8*)(pack + 16384 * 3 + fo);
    uh[ks] = *(const short8*)(pack + 16384 * 4 + fo);
    asm volatile("" : "+v"(wz[ks]));
    asm volatile("" : "+v"(uz[ks]));
    asm volatile("" : "+v"(wh[ks]));
    asm volatile("" : "+v"(uh[ks]));
  }
  float bzv = bz[c];
  float bhv = bh[c];

  f32x4 stC[2];
  stC[0] = (f32x4){0.f, 0.f, 0.f, 0.f};
  stC[1] = (f32x4){0.f, 0.f, 0.f, 0.f};

#pragma unroll
  for (int t = 0; t < T_STEPS; t++) {
    unsigned short* hB = Hb[t & 1];
    unsigned short* sB = Sb[t & 1];
#pragma unroll
    for (int rt = 0; rt < 2; rt++) {
      unsigned s01 = cvt_pk_bf16(stC[rt][0], stC[rt][1]);
      unsigned s23 = cvt_pk_bf16(stC[rt][2], stC[rt][3]);
      int rbase = (rt * 16 + q * 4) * 136 + c;
      hB[rbase + 0 * 136] = (unsigned short)hpk[rt][t][0];
      hB[rbase + 1 * 136] = (unsigned short)(hpk[rt][t][0] >> 16);
      hB[rbase + 2 * 136] = (unsigned short)hpk[rt][t][1];
      hB[rbase + 3 * 136] = (unsigned short)(hpk[rt][t][1] >> 16);
      sB[rbase + 0 * 136] = (unsigned short)s01;
      sB[rbase + 1 * 136] = (unsigned short)(s01 >> 16);
      sB[rbase + 2 * 136] = (unsigned short)s23;
      sB[rbase + 3 * 136] = (unsigned short)(s23 >> 16);
    }
    __syncthreads();

#pragma unroll
    for (int rt = 0; rt < 2; rt++) {
      int rb = (rt * 16 + l15) * 136 + q * 8;
      short8 hA[4], sA[4];
#pragma unroll
      for (int ks = 0; ks < 4; ks++) {
        hA[ks] = *(const short8*)&hB[rb + ks * 32];
        sA[ks] = *(const short8*)&sB[rb + ks * 32];
      }
      f32x4 accz = (f32x4){bzv, bzv, bzv, bzv};
      f32x4 accc = (f32x4){bhv, bhv, bhv, bhv};
#pragma unroll
      for (int ks = 0; ks < 4; ks++) {
        accz = __builtin_amdgcn_mfma_f32_16x16x32_bf16(hA[ks], wz[ks], accz, 0, 0, 0);
        accz = __builtin_amdgcn_mfma_f32_16x16x32_bf16(sA[ks], uz[ks], accz, 0, 0, 0);
        accc = __builtin_amdgcn_mfma_f32_16x16x32_bf16(hA[ks], wh[ks], accc, 0, 0, 0);
        accc = __builtin_amdgcn_mfma_f32_16x16x32_bf16(sA[ks], uh[ks], accc, 0, 0, 0);
      }
#pragma unroll
      for (int r = 0; r < 4; r++) {
        float z = fast_sig(accz[r]);
        float cc = fast_tanh(accc[r]);
        stC[rt][r] = (1.f - z) * stC[rt][r] + z * cc;
      }
    }
  }

  // final state -> out (fp32, C-layout positions)
#pragma unroll
  for (int rt = 0; rt < 2; rt++)
#pragma unroll
    for (int r = 0; r < 4; r++)
      out[(size_t)(row0 + rt * 16 + q * 4 + r) * DIM + c] = stC[rt][r];
}

extern "C" void kernel_launch(void* const* d_in, const int* in_sizes, int n_in,
                              void* d_out, int out_size, void* d_ws, size_t ws_size,
                              hipStream_t stream) {
  const int* eidx  = (const int*)d_in[0];
  const int* src   = eidx;
  const int* dst   = eidx + N_EDGES;
  const int* etype = (const int*)d_in[1];
  const int* etime = (const int*)d_in[2];
  const float* ew   = (const float*)d_in[3];
  const float* nemb = (const float*)d_in[4];
  const float* remb = (const float*)d_in[5];
  const float* Wenc = (const float*)d_in[6];
  const float* Wz   = (const float*)d_in[7];
  const float* Uz   = (const float*)d_in[8];
  const float* Wh   = (const float*)d_in[9];
  const float* Uh   = (const float*)d_in[10];
  const float* bz   = (const float*)d_in[11];
  const float* bh   = (const float*)d_in[12];
  // d_in[13] = num_times (constant 8 for this problem's fixed shapes)

  // ws layout
  unsigned short* aggb = (unsigned short*)d_ws;                    // 8*20000*128 bf16 (41 MB)
  int* counts = (int*)(aggb + (size_t)T_STEPS * N_NODES * DIM);    // SCAN_N
  int* cursor = counts + SCAN_N;                                   // KEYS
  int* bsum   = cursor + KEYS;                                     // 256
  int* base   = bsum + 256;                                        // SCAN_N
  uint2* ep2  = (uint2*)(base + ((SCAN_N + 1) & ~1));              // E, 8B-aligned
  unsigned short* pack = (unsigned short*)(ep2 + N_EDGES);         // 5*16384
  float* outp = (float*)d_out;

  hipMemsetAsync(counts, 0, (size_t)(SCAN_N + KEYS) * sizeof(int), stream);
  repack5<<<(5 * 16384 + 255) / 256, 256, 0, stream>>>(Wenc, Wz, Uz, Wh, Uh, pack);
  hist_k<<<(N_EDGES + 255) / 256, 256, 0, stream>>>(dst, etime, counts);
  scan1_k<<<SCAN_BLKS, 256, 0, stream>>>(counts, base, bsum);
  scan2_k<<<1, 256, 0, stream>>>(bsum);
  scan3_k<<<(SCAN_N + 255) / 256, 256, 0, stream>>>(base, bsum);
  fill_k<<<(N_EDGES + 255) / 256, 256, 0, stream>>>(src, dst, etype, etime, ew,
                                                    base, cursor, ep2);
  gather_k<<<N_NODES / 4, 256, 0, stream>>>(base, ep2, nemb, remb, aggb);
  fused_recur<<<N_TILES32, 512, 0, stream>>>(aggb, pack, bz, bh, outp);
}

// Round 6
// 213.110 us; speedup vs baseline: 1.1870x; 1.1870x over previous
//
#include <hip/hip_runtime.h>

#define N_NODES 20000
#define N_REL 200
#define N_EDGES 200000
#define DIM 128
#define T_STEPS 8
#define N_TILES (N_NODES / 16)              // 1250
#define KEYS (N_NODES * T_STEPS)            // 160000 (dst,t) segments
#define SCAN_N (KEYS + 1)                   // 160001
#define SCAN_BLKS ((SCAN_N + 1023) / 1024)  // 157

typedef short short8 __attribute__((ext_vector_type(8)));
typedef float f32x4 __attribute__((ext_vector_type(4)));

static __device__ __forceinline__ unsigned short f2bf(float f) {
  union { float f; unsigned u; } v; v.f = f;
  unsigned r = v.u + 0x7fffu + ((v.u >> 16) & 1u);   // RNE
  return (unsigned short)(r >> 16);
}
// packed f32x2 -> bf16x2 (RNE), 1 instruction
static __device__ __forceinline__ unsigned cvt_pk_bf16(float lo, float hi) {
  unsigned r;
  asm("v_cvt_pk_bf16_f32 %0, %1, %2" : "=v"(r) : "v"(lo), "v"(hi));
  return r;
}
static __device__ __forceinline__ float fast_tanh(float x) {
  float e = __expf(2.f * x);           // inf-safe: x>>0 -> 1, x<<0 -> -1
  return 1.f - 2.f / (e + 1.f);
}
static __device__ __forceinline__ float fast_sig(float x) {
  return 1.f / (1.f + __expf(-x));
}

// ---------------------------------------------------------------------------
// Repack the five 128x128 fp32 weight matrices (row-major W[k][n]) into bf16
// MFMA B-fragment order: pack[m][((nt*4+ks)*64+lane)*8+j] = bf16(W[k][n]),
// n = nt*16 + (lane&15), k = ks*32 + (lane>>4)*8 + j.
// Slots: 0=Wenc 1=Wz 2=Uz 3=Wh 4=Uh.
// ---------------------------------------------------------------------------
__global__ void repack5(const float* __restrict__ w0,
                        const float* __restrict__ w1,
                        const float* __restrict__ w2,
                        const float* __restrict__ w3,
                        const float* __restrict__ w4,
                        unsigned short* __restrict__ pack) {
  int i = blockIdx.x * blockDim.x + threadIdx.x;
  if (i >= 5 * 16384) return;
  int m = i >> 14, r = i & 16383;
  int j = r & 7, lane = (r >> 3) & 63, ks = (r >> 9) & 3, nt = (r >> 11) & 7;
  int n = nt * 16 + (lane & 15);
  int k = ks * 32 + (lane >> 4) * 8 + j;
  const float* w = (m == 0) ? w0 : (m == 1) ? w1 : (m == 2) ? w2
                 : (m == 3) ? w3 : w4;
  pack[i] = f2bf(w[k * DIM + n]);
}

// ----------------- CSR build: bucket by key = dst*8 + t --------------------
__global__ void hist_k(const int* __restrict__ dst, const int* __restrict__ etime,
                       int* __restrict__ counts) {
  int i = blockIdx.x * blockDim.x + threadIdx.x;
  if (i >= N_EDGES) return;
  atomicAdd(&counts[dst[i] * T_STEPS + etime[i]], 1);
}

__global__ void scan1_k(const int* __restrict__ counts,
                        int* __restrict__ base, int* __restrict__ bsum) {
  __shared__ int ls[256];
  int tid = threadIdx.x;
  int i0 = blockIdx.x * 1024 + tid * 4;
  int v[4], ts = 0;
#pragma unroll
  for (int r = 0; r < 4; r++) {
    v[r] = (i0 + r < SCAN_N) ? counts[i0 + r] : 0;
    ts += v[r];
  }
  ls[tid] = ts; __syncthreads();
#pragma unroll
  for (int off = 1; off < 256; off <<= 1) {
    int x = (tid >= off) ? ls[tid - off] : 0;
    __syncthreads(); ls[tid] += x; __syncthreads();
  }
  int run = ls[tid] - ts;
  if (tid == 255) bsum[blockIdx.x] = ls[255];
#pragma unroll
  for (int r = 0; r < 4; r++) {
    if (i0 + r < SCAN_N) base[i0 + r] = run;
    run += v[r];
  }
}

__global__ void scan2_k(int* __restrict__ bsum) {
  __shared__ int ls[256];
  int tid = threadIdx.x;
  int v = (tid < SCAN_BLKS) ? bsum[tid] : 0;
  ls[tid] = v; __syncthreads();
#pragma unroll
  for (int off = 1; off < 256; off <<= 1) {
    int x = (tid >= off) ? ls[tid - off] : 0;
    __syncthreads(); ls[tid] += x; __syncthreads();
  }
  if (tid < SCAN_BLKS) bsum[tid] = ls[tid] - v;
}

// ep2 = {src | rel<<15, weight bits}; t is implicit in the segment.
// scan3 folded in: absolute position = base[key] + bsum[key>>10] + cursor++.
__global__ void fill_k(const int* __restrict__ src, const int* __restrict__ dst,
                       const int* __restrict__ etype, const int* __restrict__ etime,
                       const float* __restrict__ ew,
                       const int* __restrict__ base, const int* __restrict__ bsum,
                       int* __restrict__ cursor, uint2* __restrict__ ep2) {
  int i = blockIdx.x * blockDim.x + threadIdx.x;
  if (i >= N_EDGES) return;
  int key = dst[i] * T_STEPS + etime[i];
  int pos = base[key] + bsum[key >> 10] + atomicAdd(&cursor[key], 1);
  uint2 e;
  e.x = (unsigned)src[i] | ((unsigned)etype[i] << 15);
  e.y = __float_as_uint(ew[i]);
  ep2[pos] = e;
}

// ---------------------------------------------------------------------------
// Fully-fused GATHER + encoder + GRU recurrence. One block per 16-node tile,
// 8 waves. Eliminates gather_k and the 41 MB aggb global round-trip: agg
// rows are built straight into LDS.
// Phase A (gather): wave wv owns local nodes {2wv, 2wv+1}; for each node the
//   8 (dst,t) CSR segments are contiguous -> plain FMA loop per segment;
//   each lane holds dims (2*lane, 2*lane+1); packed bf16 row written to
//   aggL[(t*16+node_local)*136] (u32/lane, contiguous 256B -> conflict-free).
// ONE barrier, then:
// Phase B (encoder, hoisted): wave wv owns column tile nt=wv; A-frags for
//   all 8 t read from aggL (stride 136 shorts = 272B -> rows land on banks
//   4*row%32, 2-way alias = free; 16B-aligned b128 reads). 32 MFMAs with
//   wenc -> hpk[t] packed bf16 (16 VGPRs).
// Phase C (recurrence, as best-measured R1): per step t: H[t],S -> double-
//   buffered LDS (stride 136), ONE barrier, re-read as A-frags (full 128-K),
//   16 MFMAs, gated update.
// MFMA 16x16x32_bf16 layouts (HW-verified): A: m=lane&15,k=quad*8+j;
// B: n=lane&15,k=quad*8+j;  C/D: col=lane&15, row=quad*4+reg.
// Double-buffer WAR safety: writes of buffer X at step t+2 are ordered after
// barrier(t+1), which is after all reads of X at step t. aggL is written
// only in phase A (barrier-protected) and read-only afterwards.
// ---------------------------------------------------------------------------
__launch_bounds__(512, 4)
__global__ void fused_recur(const int* __restrict__ base,
                            const int* __restrict__ bsum,
                            const uint2* __restrict__ ep2,
                            const float* __restrict__ nemb,
                            const float* __restrict__ remb,
                            const unsigned short* __restrict__ pack,
                            const float* __restrict__ bz,
                            const float* __restrict__ bh,
                            float* __restrict__ out) {
  __shared__ unsigned short aggL[T_STEPS * 16 * 136];   // 34816 B
  __shared__ unsigned short Hb[2][16 * 136];            //  8704 B
  __shared__ unsigned short Sb[2][16 * 136];            //  8704 B
  int lane = threadIdx.x & 63;
  int nt = threadIdx.x >> 6;        // wave id: gather-node pair / column tile
  int q = lane >> 4, l15 = lane & 15;
  int row0 = blockIdx.x * 16;
  int c = nt * 16 + l15;

  // ---- Phase A: gather this wave's 2 nodes, all 8 t-segments -> aggL ----
#pragma unroll
  for (int ln = 0; ln < 2; ln++) {
    int nl = nt * 2 + ln;                       // local row 0..15
    int kb = (row0 + nl) * T_STEPS;
    int prev = base[kb] + bsum[kb >> 10];
#pragma unroll
    for (int tt = 0; tt < T_STEPS; tt++) {
      int kn = kb + tt + 1;
      int e1 = base[kn] + bsum[kn >> 10];
      float ax = 0.f, ay = 0.f;
      for (int i = prev; i < e1; i++) {
        uint2 e = ep2[i];
        float w = __uint_as_float(e.y);
        int s = e.x & 0x7fff, rt = e.x >> 15;
        float2 sv = ((const float2*)(nemb + (size_t)s * DIM))[lane];
        float2 rv = ((const float2*)(remb + (size_t)rt * DIM))[lane];
        ax += sv.x * rv.x * w;
        ay += sv.y * rv.y * w;
      }
      prev = e1;
      ((unsigned*)&aggL[(tt * 16 + nl) * 136])[lane] = cvt_pk_bf16(ax, ay);
    }
  }
  __syncthreads();

  // ---- Phase B: encoder for ALL steps: H[t](:, nt-cols) as packed bf16 ----
  unsigned hpk[T_STEPS][2];
  {
    short8 wenc[4];
#pragma unroll
    for (int ks = 0; ks < 4; ks++)
      wenc[ks] = *(const short8*)(pack + ((nt * 4 + ks) * 64 + lane) * 8);
#pragma unroll
    for (int t = 0; t < T_STEPS; t++) {
      f32x4 acch = (f32x4){0.f, 0.f, 0.f, 0.f};
#pragma unroll
      for (int ks = 0; ks < 4; ks++) {
        short8 aA = *(const short8*)&aggL[(t * 16 + l15) * 136 + ks * 32 + q * 8];
        acch = __builtin_amdgcn_mfma_f32_16x16x32_bf16(aA, wenc[ks], acch, 0, 0, 0);
      }
      hpk[t][0] = cvt_pk_bf16(fast_tanh(acch[0]), fast_tanh(acch[1]));
      hpk[t][1] = cvt_pk_bf16(fast_tanh(acch[2]), fast_tanh(acch[3]));
    }
  }

  // recurrence weight B-fragments for this wave's nt
  short8 wz[4], uz[4], wh[4], uh[4];
#pragma unroll
  for (int ks = 0; ks < 4; ks++) {
    int fo = ((nt * 4 + ks) * 64 + lane) * 8;
    wz[ks] = *(const short8*)(pack + 16384 * 1 + fo);
    uz[ks] = *(const short8*)(pack + 16384 * 2 + fo);
    wh[ks] = *(const short8*)(pack + 16384 * 3 + fo);
    uh[ks] = *(const short8*)(pack + 16384 * 4 + fo);
  }
  float bzv = bz[c];
  float bhv = bh[c];

  f32x4 stC = (f32x4){0.f, 0.f, 0.f, 0.f};

  // ---- Phase C: GRU recurrence (best-measured R1 structure) ----
#pragma unroll
  for (int t = 0; t < T_STEPS; t++) {
    unsigned short* hB = Hb[t & 1];
    unsigned short* sB = Sb[t & 1];
    unsigned s01 = cvt_pk_bf16(stC[0], stC[1]);
    unsigned s23 = cvt_pk_bf16(stC[2], stC[3]);
    hB[(q * 4 + 0) * 136 + c] = (unsigned short)hpk[t][0];
    hB[(q * 4 + 1) * 136 + c] = (unsigned short)(hpk[t][0] >> 16);
    hB[(q * 4 + 2) * 136 + c] = (unsigned short)hpk[t][1];
    hB[(q * 4 + 3) * 136 + c] = (unsigned short)(hpk[t][1] >> 16);
    sB[(q * 4 + 0) * 136 + c] = (unsigned short)s01;
    sB[(q * 4 + 1) * 136 + c] = (unsigned short)(s01 >> 16);
    sB[(q * 4 + 2) * 136 + c] = (unsigned short)s23;
    sB[(q * 4 + 3) * 136 + c] = (unsigned short)(s23 >> 16);
    __syncthreads();

    f32x4 accz = (f32x4){bzv, bzv, bzv, bzv};
    f32x4 accc = (f32x4){bhv, bhv, bhv, bhv};
#pragma unroll
    for (int ks = 0; ks < 4; ks++) {
      short8 hA = *(const short8*)&hB[l15 * 136 + ks * 32 + q * 8];
      short8 sA = *(const short8*)&sB[l15 * 136 + ks * 32 + q * 8];
      accz = __builtin_amdgcn_mfma_f32_16x16x32_bf16(hA, wz[ks], accz, 0, 0, 0);
      accz = __builtin_amdgcn_mfma_f32_16x16x32_bf16(sA, uz[ks], accz, 0, 0, 0);
      accc = __builtin_amdgcn_mfma_f32_16x16x32_bf16(hA, wh[ks], accc, 0, 0, 0);
      accc = __builtin_amdgcn_mfma_f32_16x16x32_bf16(sA, uh[ks], accc, 0, 0, 0);
    }
#pragma unroll
    for (int r = 0; r < 4; r++) {
      float z = fast_sig(accz[r]);
      float cc = fast_tanh(accc[r]);
      stC[r] = (1.f - z) * stC[r] + z * cc;
    }
  }

  // final state -> out (fp32, C-layout positions)
#pragma unroll
  for (int r = 0; r < 4; r++)
    out[(size_t)(row0 + q * 4 + r) * DIM + c] = stC[r];
}

extern "C" void kernel_launch(void* const* d_in, const int* in_sizes, int n_in,
                              void* d_out, int out_size, void* d_ws, size_t ws_size,
                              hipStream_t stream) {
  const int* eidx  = (const int*)d_in[0];
  const int* src   = eidx;
  const int* dst   = eidx + N_EDGES;
  const int* etype = (const int*)d_in[1];
  const int* etime = (const int*)d_in[2];
  const float* ew   = (const float*)d_in[3];
  const float* nemb = (const float*)d_in[4];
  const float* remb = (const float*)d_in[5];
  const float* Wenc = (const float*)d_in[6];
  const float* Wz   = (const float*)d_in[7];
  const float* Uz   = (const float*)d_in[8];
  const float* Wh   = (const float*)d_in[9];
  const float* Uh   = (const float*)d_in[10];
  const float* bz   = (const float*)d_in[11];
  const float* bh   = (const float*)d_in[12];
  // d_in[13] = num_times (constant 8 for this problem's fixed shapes)

  // ws layout (no aggb anymore)
  int* counts = (int*)d_ws;                                        // SCAN_N
  int* cursor = counts + SCAN_N;                                   // KEYS
  int* bsum   = cursor + KEYS;                                     // 256
  int* base   = bsum + 256;                                        // SCAN_N
  uint2* ep2  = (uint2*)(base + ((SCAN_N + 1) & ~1));              // E, 8B-aligned
  unsigned short* pack = (unsigned short*)(ep2 + N_EDGES);         // 5*16384
  float* outp = (float*)d_out;

  hipMemsetAsync(counts, 0, (size_t)(SCAN_N + KEYS) * sizeof(int), stream);
  repack5<<<(5 * 16384 + 255) / 256, 256, 0, stream>>>(Wenc, Wz, Uz, Wh, Uh, pack);
  hist_k<<<(N_EDGES + 255) / 256, 256, 0, stream>>>(dst, etime, counts);
  scan1_k<<<SCAN_BLKS, 256, 0, stream>>>(counts, base, bsum);
  scan2_k<<<1, 256, 0, stream>>>(bsum);
  fill_k<<<(N_EDGES + 255) / 256, 256, 0, stream>>>(src, dst, etype, etime, ew,
                                                    base, bsum, cursor, ep2);
  fused_recur<<<N_TILES, 512, 0, stream>>>(base, bsum, ep2, nemb, remb,
                                           pack, bz, bh, outp);
}